// Round 1
// baseline (457.461 us; speedup 1.0000x reference)
//
#include <hip/hip_runtime.h>

#define NB 64      // batch
#define NN 1024    // nodes
#define ND 128     // feature dim
#define NH 64      // hidden dim

typedef __attribute__((ext_vector_type(4))) float f32x4;
typedef __attribute__((ext_vector_type(8))) __bf16 bf16x8;

__device__ __forceinline__ ushort f2bf(float f) {
  unsigned u = __float_as_uint(f);
  u += 0x7fffu + ((u >> 16) & 1u);   // RNE to bf16
  return (ushort)(u >> 16);
}

// Kernel 1: txt[b][d][n] = bf16(tanh(x[b][n][d]))  (transposed for B-fragments)
// Also zero the per-batch logit accumulator.
__global__ __launch_bounds__(256) void prep_kernel(const float* __restrict__ x,
                                                   ushort* __restrict__ txt,
                                                   float* __restrict__ acc) {
  if (blockIdx.x == 0 && blockIdx.y == 0 && blockIdx.z == 0 && threadIdx.x < NB)
    acc[threadIdx.x] = 0.0f;
  __shared__ ushort tile[64][72];          // [n_local][d_local], padded
  int b = blockIdx.z;
  int n0 = blockIdx.x * 64;
  int d0 = blockIdx.y * 64;
  int tid = threadIdx.x;
  int r = tid >> 2;                        // 0..63
  int cseg = (tid & 3) * 16;               // 0,16,32,48
  const float* xp = x + ((size_t)b * NN + n0 + r) * ND + d0 + cseg;
  #pragma unroll
  for (int i = 0; i < 16; i += 4) {
    float4 v = *(const float4*)(xp + i);
    ushort4 w;
    w.x = f2bf(tanhf(v.x)); w.y = f2bf(tanhf(v.y));
    w.z = f2bf(tanhf(v.z)); w.w = f2bf(tanhf(v.w));
    *(ushort4*)&tile[r][cseg + i] = w;
  }
  __syncthreads();
  // write transposed: this thread owns d-row (d0+r), n range [n0+cseg, +16)
  ushort* op = txt + ((size_t)b * ND + d0 + r) * NN + n0 + cseg;
  #pragma unroll
  for (int i = 0; i < 16; i += 4) {
    ushort4 w;
    w.x = tile[cseg + i + 0][r];
    w.y = tile[cseg + i + 1][r];
    w.z = tile[cseg + i + 2][r];
    w.w = tile[cseg + i + 3][r];
    *(ushort4*)(op + i) = w;
  }
}

// Kernel 2: per batch, msg = L @ tanh(x); tmsg[b][n][d] = bf16(tanh(msg))
// Block tile 64(M) x 128(N=D), BK=64. 4 waves in 2x2; wave tile 32x64.
__global__ __launch_bounds__(256) void msg_kernel(const float* __restrict__ L,
                                                  const ushort* __restrict__ txt,
                                                  ushort* __restrict__ tmsg) {
  __shared__ ushort As[64][72];    // L tile, bf16, row-major [m][k]
  __shared__ ushort Bs[128][72];   // txt tile, [d][k] (k-contiguous)
  int b = blockIdx.y;
  int brow = blockIdx.x * 64;
  int tid = threadIdx.x;
  int wave = tid >> 6, lane = tid & 63;
  int wm = (wave >> 1) * 32;       // 0 / 32
  int wn = (wave & 1) * 64;        // 0 / 64
  int l15 = lane & 15;
  int kof = (lane >> 4) * 8;
  const float*  Lp = L   + (size_t)b * NN * NN;
  const ushort* Bp = txt + (size_t)b * ND * NN;
  f32x4 acc[2][4] = {};
  int ar = tid >> 2, aseg = (tid & 3) * 16;   // A staging: row, 16-float seg
  int bd = tid >> 1, bseg = (tid & 1) * 32;   // B staging: d-row, 32-bf16 seg
  for (int k0 = 0; k0 < NN; k0 += 64) {
    const float* ap = Lp + (size_t)(brow + ar) * NN + k0 + aseg;
    #pragma unroll
    for (int i = 0; i < 16; i += 4) {
      float4 v = *(const float4*)(ap + i);
      ushort4 w;
      w.x = f2bf(v.x); w.y = f2bf(v.y); w.z = f2bf(v.z); w.w = f2bf(v.w);
      *(ushort4*)&As[ar][aseg + i] = w;
    }
    const float4* bp = (const float4*)(Bp + (size_t)bd * NN + k0 + bseg);
    #pragma unroll
    for (int i = 0; i < 4; ++i)
      *(float4*)&Bs[bd][bseg + i * 8] = bp[i];
    __syncthreads();
    #pragma unroll
    for (int kk = 0; kk < 2; ++kk) {
      int kb = kk * 32 + kof;
      bf16x8 a0 = *(const bf16x8*)&As[wm + l15][kb];
      bf16x8 a1 = *(const bf16x8*)&As[wm + 16 + l15][kb];
      #pragma unroll
      for (int nt = 0; nt < 4; ++nt) {
        bf16x8 bb = *(const bf16x8*)&Bs[wn + nt * 16 + l15][kb];
        acc[0][nt] = __builtin_amdgcn_mfma_f32_16x16x32_bf16(a0, bb, acc[0][nt], 0, 0, 0);
        acc[1][nt] = __builtin_amdgcn_mfma_f32_16x16x32_bf16(a1, bb, acc[1][nt], 0, 0, 0);
      }
    }
    __syncthreads();
  }
  ushort* op = tmsg + (size_t)b * NN * ND;
  #pragma unroll
  for (int mt = 0; mt < 2; ++mt)
    #pragma unroll
    for (int nt = 0; nt < 4; ++nt)
      #pragma unroll
      for (int rr = 0; rr < 4; ++rr) {
        int row = brow + wm + mt * 16 + (lane >> 4) * 4 + rr;
        int col = wn + nt * 16 + l15;
        op[(size_t)row * ND + col] = f2bf(tanhf(acc[mt][nt][rr]));
      }
}

// Kernel 3: state = tanh(x@W1 + tmsg@W2); s = state.Wl; sum s over rows -> acc[b]
// Block: 64 rows of one batch. 4 waves, wave w owns rows [16w,16w+16), all 64 h.
__global__ __launch_bounds__(256) void state_kernel(const float* __restrict__ x,
                                                    const ushort* __restrict__ tmsg,
                                                    const float* __restrict__ W1,
                                                    const float* __restrict__ W2,
                                                    const float* __restrict__ Wl,
                                                    float* __restrict__ acc) {
  __shared__ ushort W1t[64][136];  // [h][d] bf16
  __shared__ ushort W2t[64][136];
  __shared__ ushort Xs[64][136];   // x rows, bf16
  __shared__ ushort Ts[64][136];   // tmsg rows, bf16
  __shared__ float Wls[64];
  int b = blockIdx.y;
  int n0 = blockIdx.x * 64;
  int tid = threadIdx.x;
  for (int i = tid; i < ND * NH; i += 256) {
    int d = i >> 6, h = i & 63;    // W1 is [D][H] row-major
    W1t[h][d] = f2bf(W1[i]);
    W2t[h][d] = f2bf(W2[i]);
  }
  if (tid < NH) Wls[tid] = Wl[tid];
  int r = tid >> 2, seg = (tid & 3) * 32;
  const float* xp = x + ((size_t)b * NN + n0 + r) * ND + seg;
  #pragma unroll
  for (int i = 0; i < 32; i += 4) {
    float4 v = *(const float4*)(xp + i);
    ushort4 w;
    w.x = f2bf(v.x); w.y = f2bf(v.y); w.z = f2bf(v.z); w.w = f2bf(v.w);
    *(ushort4*)&Xs[r][seg + i] = w;
  }
  const ushort* tp = tmsg + ((size_t)b * NN + n0 + r) * ND + seg;
  #pragma unroll
  for (int i = 0; i < 4; ++i)
    *(float4*)&Ts[r][seg + i * 8] = *(const float4*)(tp + i * 8);
  __syncthreads();
  int wave = tid >> 6, lane = tid & 63;
  int l15 = lane & 15, kof = (lane >> 4) * 8;
  int arow = wave * 16 + l15;
  f32x4 acc4[4] = {};
  #pragma unroll
  for (int kk = 0; kk < 4; ++kk) {
    int kb = kk * 32 + kof;
    bf16x8 ax = *(const bf16x8*)&Xs[arow][kb];
    bf16x8 at = *(const bf16x8*)&Ts[arow][kb];
    #pragma unroll
    for (int nt = 0; nt < 4; ++nt) {
      bf16x8 b1 = *(const bf16x8*)&W1t[nt * 16 + l15][kb];
      bf16x8 b2 = *(const bf16x8*)&W2t[nt * 16 + l15][kb];
      acc4[nt] = __builtin_amdgcn_mfma_f32_16x16x32_bf16(ax, b1, acc4[nt], 0, 0, 0);
      acc4[nt] = __builtin_amdgcn_mfma_f32_16x16x32_bf16(at, b2, acc4[nt], 0, 0, 0);
    }
  }
  // lane holds rows (wave*16 + (lane>>4)*4 + rr), cols h = nt*16 + l15.
  // Sum over all 64 lanes covers 16 rows x 64 h exactly once.
  float ssum = 0.0f;
  #pragma unroll
  for (int rr = 0; rr < 4; ++rr) {
    #pragma unroll
    for (int nt = 0; nt < 4; ++nt) {
      float st = tanhf(acc4[nt][rr]);
      ssum += st * Wls[nt * 16 + l15];
    }
  }
  #pragma unroll
  for (int off = 32; off >= 1; off >>= 1)
    ssum += __shfl_xor(ssum, off);
  if (lane == 0) atomicAdd(&acc[b], ssum);
}

// Kernel 4: loss = mean_b log1p(exp(-(acc[b]/(N*H)) * label[b]))
__global__ void final_kernel(const float* __restrict__ acc,
                             const float* __restrict__ label,
                             float* __restrict__ out) {
  int t = threadIdx.x;
  float v = 0.0f;
  if (t < NB) {
    float logit = acc[t] * (1.0f / ((float)NN * (float)NH));
    float z = -logit * label[t];
    v = log1pf(expf(z));
  }
  #pragma unroll
  for (int off = 32; off >= 1; off >>= 1)
    v += __shfl_xor(v, off);
  if (t == 0) out[0] = v * (1.0f / (float)NB);
}

extern "C" void kernel_launch(void* const* d_in, const int* in_sizes, int n_in,
                              void* d_out, int out_size, void* d_ws, size_t ws_size,
                              hipStream_t stream) {
  const float* x     = (const float*)d_in[0];   // [B,N,D]
  const float* L     = (const float*)d_in[1];   // [B,N,N]
  const float* label = (const float*)d_in[2];   // [B]
  const float* W1    = (const float*)d_in[3];   // [D,H]
  const float* W2    = (const float*)d_in[4];   // [D,H]
  const float* Wl    = (const float*)d_in[5];   // [H,1]
  float* out = (float*)d_out;

  char* ws = (char*)d_ws;
  ushort* txt  = (ushort*)ws;                          // [B][D][N] bf16, 16 MB
  ushort* tmsg = (ushort*)(ws + (size_t)16777216);     // [B][N][D] bf16, 16 MB
  float*  acc  = (float*)(ws + (size_t)33554432);      // [B] fp32

  prep_kernel<<<dim3(NN / 64, ND / 64, NB), 256, 0, stream>>>(x, txt, acc);
  msg_kernel<<<dim3(NN / 64, NB), 256, 0, stream>>>(L, txt, tmsg);
  state_kernel<<<dim3(NN / 64, NB), 256, 0, stream>>>(x, tmsg, W1, W2, Wl, acc);
  final_kernel<<<1, 64, 0, stream>>>(acc, label, out);
}

// Round 3
// 456.226 us; speedup vs baseline: 1.0027x; 1.0027x over previous
//
#include <hip/hip_runtime.h>

#define NB 64      // batch
#define NN 1024    // nodes
#define ND 128     // feature dim
#define NH 64      // hidden dim

typedef __attribute__((ext_vector_type(4))) float f32x4;
typedef __attribute__((ext_vector_type(8))) __bf16 bf16x8;

__device__ __forceinline__ ushort f2bf(float f) {
  unsigned u = __float_as_uint(f);
  u += 0x7fffu + ((u >> 16) & 1u);   // RNE to bf16
  return (ushort)(u >> 16);
}

#define GLOAD16(g, l)                                                          \
  __builtin_amdgcn_global_load_lds(                                            \
      (const __attribute__((address_space(1))) void*)(g),                      \
      (__attribute__((address_space(3))) void*)(l), 16, 0, 0)

// Kernel 1: txt[b][d][n] = bf16(tanh(x[b][n][d]))  (transposed for B-fragments)
// Also zero the per-batch logit accumulator.
__global__ __launch_bounds__(256) void prep_kernel(const float* __restrict__ x,
                                                   ushort* __restrict__ txt,
                                                   float* __restrict__ acc) {
  if (blockIdx.x == 0 && blockIdx.y == 0 && blockIdx.z == 0 && threadIdx.x < NB)
    acc[threadIdx.x] = 0.0f;
  __shared__ ushort tile[64][72];          // [n_local][d_local], padded
  int b = blockIdx.z;
  int n0 = blockIdx.x * 64;
  int d0 = blockIdx.y * 64;
  int tid = threadIdx.x;
  int r = tid >> 2;                        // 0..63
  int cseg = (tid & 3) * 16;               // 0,16,32,48
  const float* xp = x + ((size_t)b * NN + n0 + r) * ND + d0 + cseg;
  #pragma unroll
  for (int i = 0; i < 16; i += 4) {
    float4 v = *(const float4*)(xp + i);
    ushort4 w;
    w.x = f2bf(tanhf(v.x)); w.y = f2bf(tanhf(v.y));
    w.z = f2bf(tanhf(v.z)); w.w = f2bf(tanhf(v.w));
    *(ushort4*)&tile[r][cseg + i] = w;
  }
  __syncthreads();
  // write transposed: this thread owns d-row (d0+r), n range [n0+cseg, +16)
  ushort* op = txt + ((size_t)b * ND + d0 + r) * NN + n0 + cseg;
  #pragma unroll
  for (int i = 0; i < 16; i += 4) {
    ushort4 w;
    w.x = tile[cseg + i + 0][r];
    w.y = tile[cseg + i + 1][r];
    w.z = tile[cseg + i + 2][r];
    w.w = tile[cseg + i + 3][r];
    *(ushort4*)(op + i) = w;
  }
}

// Kernel 2: per batch, msg = L @ tanh(x); tmsg[b][n][d] = bf16(tanh(msg))
// m97-style: tile 64(M) x 128(N=D), BK=64, global_load_lds for both operands.
// A = L staged as raw fp32 (converted to bf16 at consume), B = txt bf16 [d][n].
// 4 waves in 2x2; wave tile 32x64 (2x4 fragments of 16x16).
__global__ __launch_bounds__(256) void msg_kernel(const float* __restrict__ L,
                                                  const ushort* __restrict__ txt,
                                                  ushort* __restrict__ tmsg) {
  __shared__ float  As[64 * 64];    // [m][k] fp32, 16 KB, linear (gload_lds dest)
  __shared__ ushort Bs[128 * 64];   // [d][k] bf16, 16 KB, linear
  int b = blockIdx.y;
  int brow = blockIdx.x * 64;
  int tid = threadIdx.x;
  int wave = tid >> 6, lane = tid & 63;
  int l15 = lane & 15;
  int kof = (lane >> 4) * 8;
  int wm = (wave >> 1) * 32;        // 0 / 32
  int wn = (wave & 1) * 64;         // 0 / 64

  const char* Lb = (const char*)(L + (size_t)b * NN * NN + (size_t)brow * NN);
  const char* Tb = (const char*)(txt + (size_t)b * ND * NN);

  // A staging: 16 rounds of 1KB (4 per wave). Round q: rows q*4 + (lane>>4),
  // 16B chunk (lane&15)*16 within the 256B row-chunk. LDS byte = q*1024 + lane*16.
  // B staging: 16 rounds (4 per wave). Round q: rows q*8 + (lane>>3),
  // 16B chunk (lane&7)*16 within the 128B row-chunk.
  const char* aG = Lb + (size_t)(4 * (wave * 4) + (lane >> 4)) * (NN * 4) + l15 * 16;
  const char* bG = Tb + (size_t)(8 * (wave * 4) + (lane >> 3)) * (NN * 2) + (lane & 7) * 16;
  char* aL = (char*)As + (wave * 4) * 1024;
  char* bL = (char*)Bs + (wave * 4) * 1024;

  f32x4 acc[2][4] = {};

  for (int k0 = 0; k0 < NN; k0 += 64) {
    #pragma unroll
    for (int i = 0; i < 4; ++i)
      GLOAD16(aG + (size_t)i * 4 * (NN * 4) + (size_t)k0 * 4, aL + i * 1024);
    #pragma unroll
    for (int i = 0; i < 4; ++i)
      GLOAD16(bG + (size_t)i * 8 * (NN * 2) + (size_t)k0 * 2, bL + i * 1024);
    __syncthreads();
    #pragma unroll
    for (int kk = 0; kk < 2; ++kk) {
      int kb = kk * 32 + kof;
      bf16x8 av[2];
      #pragma unroll
      for (int mt = 0; mt < 2; ++mt) {
        const f32x4* ap = (const f32x4*)(As + (wm + mt * 16 + l15) * 64 + kb);
        f32x4 lo = ap[0], hi = ap[1];
        bf16x8 a;
        a[0] = (__bf16)lo[0]; a[1] = (__bf16)lo[1];
        a[2] = (__bf16)lo[2]; a[3] = (__bf16)lo[3];
        a[4] = (__bf16)hi[0]; a[5] = (__bf16)hi[1];
        a[6] = (__bf16)hi[2]; a[7] = (__bf16)hi[3];
        av[mt] = a;
      }
      #pragma unroll
      for (int nt = 0; nt < 4; ++nt) {
        bf16x8 bb = *(const bf16x8*)(Bs + (wn + nt * 16 + l15) * 64 + kb);
        acc[0][nt] = __builtin_amdgcn_mfma_f32_16x16x32_bf16(av[0], bb, acc[0][nt], 0, 0, 0);
        acc[1][nt] = __builtin_amdgcn_mfma_f32_16x16x32_bf16(av[1], bb, acc[1][nt], 0, 0, 0);
      }
    }
    __syncthreads();
  }

  ushort* op = tmsg + (size_t)b * NN * ND;
  #pragma unroll
  for (int mt = 0; mt < 2; ++mt)
    #pragma unroll
    for (int nt = 0; nt < 4; ++nt)
      #pragma unroll
      for (int rr = 0; rr < 4; ++rr) {
        int row = brow + wm + mt * 16 + (lane >> 4) * 4 + rr;
        int col = wn + nt * 16 + l15;
        op[(size_t)row * ND + col] = f2bf(tanhf(acc[mt][nt][rr]));
      }
}

// Kernel 3: state = tanh(x@W1 + tmsg@W2); s = state.Wl; sum s over rows -> acc[b]
__global__ __launch_bounds__(256) void state_kernel(const float* __restrict__ x,
                                                    const ushort* __restrict__ tmsg,
                                                    const float* __restrict__ W1,
                                                    const float* __restrict__ W2,
                                                    const float* __restrict__ Wl,
                                                    float* __restrict__ acc) {
  __shared__ ushort W1t[64][136];  // [h][d] bf16
  __shared__ ushort W2t[64][136];
  __shared__ ushort Xs[64][136];   // x rows, bf16
  __shared__ ushort Ts[64][136];   // tmsg rows, bf16
  __shared__ float Wls[64];
  int b = blockIdx.y;
  int n0 = blockIdx.x * 64;
  int tid = threadIdx.x;
  for (int i = tid; i < ND * NH; i += 256) {
    int d = i >> 6, h = i & 63;    // W1 is [D][H] row-major
    W1t[h][d] = f2bf(W1[i]);
    W2t[h][d] = f2bf(W2[i]);
  }
  if (tid < NH) Wls[tid] = Wl[tid];
  int r = tid >> 2, seg = (tid & 3) * 32;
  const float* xp = x + ((size_t)b * NN + n0 + r) * ND + seg;
  #pragma unroll
  for (int i = 0; i < 32; i += 4) {
    float4 v = *(const float4*)(xp + i);
    ushort4 w;
    w.x = f2bf(v.x); w.y = f2bf(v.y); w.z = f2bf(v.z); w.w = f2bf(v.w);
    *(ushort4*)&Xs[r][seg + i] = w;
  }
  const ushort* tp = tmsg + ((size_t)b * NN + n0 + r) * ND + seg;
  #pragma unroll
  for (int i = 0; i < 4; ++i)
    *(float4*)&Ts[r][seg + i * 8] = *(const float4*)(tp + i * 8);
  __syncthreads();
  int wave = tid >> 6, lane = tid & 63;
  int l15 = lane & 15, kof = (lane >> 4) * 8;
  int arow = wave * 16 + l15;
  f32x4 acc4[4] = {};
  #pragma unroll
  for (int kk = 0; kk < 4; ++kk) {
    int kb = kk * 32 + kof;
    bf16x8 ax = *(const bf16x8*)&Xs[arow][kb];
    bf16x8 at = *(const bf16x8*)&Ts[arow][kb];
    #pragma unroll
    for (int nt = 0; nt < 4; ++nt) {
      bf16x8 b1 = *(const bf16x8*)&W1t[nt * 16 + l15][kb];
      bf16x8 b2 = *(const bf16x8*)&W2t[nt * 16 + l15][kb];
      acc4[nt] = __builtin_amdgcn_mfma_f32_16x16x32_bf16(ax, b1, acc4[nt], 0, 0, 0);
      acc4[nt] = __builtin_amdgcn_mfma_f32_16x16x32_bf16(at, b2, acc4[nt], 0, 0, 0);
    }
  }
  float ssum = 0.0f;
  #pragma unroll
  for (int rr = 0; rr < 4; ++rr) {
    #pragma unroll
    for (int nt = 0; nt < 4; ++nt) {
      float st = tanhf(acc4[nt][rr]);
      ssum += st * Wls[nt * 16 + l15];
    }
  }
  #pragma unroll
  for (int off = 32; off >= 1; off >>= 1)
    ssum += __shfl_xor(ssum, off);
  if (lane == 0) atomicAdd(&acc[b], ssum);
}

// Kernel 4: loss = mean_b log1p(exp(-(acc[b]/(N*H)) * label[b]))
__global__ void final_kernel(const float* __restrict__ acc,
                             const float* __restrict__ label,
                             float* __restrict__ out) {
  int t = threadIdx.x;
  float v = 0.0f;
  if (t < NB) {
    float logit = acc[t] * (1.0f / ((float)NN * (float)NH));
    float z = -logit * label[t];
    v = log1pf(expf(z));
  }
  #pragma unroll
  for (int off = 32; off >= 1; off >>= 1)
    v += __shfl_xor(v, off);
  if (t == 0) out[0] = v * (1.0f / (float)NB);
}

extern "C" void kernel_launch(void* const* d_in, const int* in_sizes, int n_in,
                              void* d_out, int out_size, void* d_ws, size_t ws_size,
                              hipStream_t stream) {
  const float* x     = (const float*)d_in[0];   // [B,N,D]
  const float* L     = (const float*)d_in[1];   // [B,N,N]
  const float* label = (const float*)d_in[2];   // [B]
  const float* W1    = (const float*)d_in[3];   // [D,H]
  const float* W2    = (const float*)d_in[4];   // [D,H]
  const float* Wl    = (const float*)d_in[5];   // [H,1]
  float* out = (float*)d_out;

  char* ws = (char*)d_ws;
  ushort* txt  = (ushort*)ws;                          // [B][D][N] bf16, 16 MB
  ushort* tmsg = (ushort*)(ws + (size_t)16777216);     // [B][N][D] bf16, 16 MB
  float*  acc  = (float*)(ws + (size_t)33554432);      // [B] fp32

  prep_kernel<<<dim3(NN / 64, ND / 64, NB), 256, 0, stream>>>(x, txt, acc);
  msg_kernel<<<dim3(NN / 64, NB), 256, 0, stream>>>(L, txt, tmsg);
  state_kernel<<<dim3(NN / 64, NB), 256, 0, stream>>>(x, tmsg, W1, W2, Wl, acc);
  final_kernel<<<1, 64, 0, stream>>>(acc, label, out);
}